// Round 2
// baseline (299.529 us; speedup 1.0000x reference)
//
#include <hip/hip_runtime.h>
#include <math.h>

#define N_SLOTS 4096
#define DIM 256
#define HEADS 4
#define RANK 32
#define TOPK 32
#define QK 128  // HEADS*RANK

// ---- block-wide sum over 256 threads (4 waves) ----
__device__ __forceinline__ float block_sum256(float v, float* red) {
#pragma unroll
  for (int o = 32; o > 0; o >>= 1) v += __shfl_xor(v, o);
  int lane = threadIdx.x & 63, wid = threadIdx.x >> 6;
  if (lane == 0) red[wid] = v;
  __syncthreads();
  v = red[0] + red[1] + red[2] + red[3];
  __syncthreads();
  return v;
}

// ---- Kernel A: LayerNorm + unit-normalize rows of init_val -> val0 [N,D] ----
__global__ void ln_unit_kernel(const float* __restrict__ x,
                               const float* __restrict__ g,
                               const float* __restrict__ b,
                               float* __restrict__ val0) {
  __shared__ float red[4];
  int n = blockIdx.x, t = threadIdx.x;
  float v = x[n * DIM + t];
  float mean = block_sum256(v, red) * (1.0f / DIM);
  float d = v - mean;
  float var = block_sum256(d * d, red) * (1.0f / DIM);
  float y = d * rsqrtf(var + 1e-5f) * g[t] + b[t];
  float ss = block_sum256(y * y, red);
  y = y / fmaxf(sqrtf(ss), 1e-6f);
  val0[n * DIM + t] = y;
}

// ---- Kernel B: q/k projections. q[n][h*R+r] = sum_d val0[n][d]*Wq[h][d][r] ----
__global__ void qk_kernel(const float* __restrict__ val0,
                          const float* __restrict__ Wq,
                          const float* __restrict__ Wk,
                          float* __restrict__ q, float* __restrict__ k) {
  __shared__ float v[DIM];
  int n = blockIdx.x, t = threadIdx.x;  // 128 threads
  v[t] = val0[n * DIM + t];
  v[t + 128] = val0[n * DIM + t + 128];
  __syncthreads();
  int h = t >> 5, r = t & 31;
  const float* wq = Wq + (size_t)h * DIM * RANK + r;
  const float* wk = Wk + (size_t)h * DIM * RANK + r;
  float aq = 0.f, ak = 0.f;
#pragma unroll 4
  for (int d = 0; d < DIM; ++d) {
    float vv = v[d];
    aq = fmaf(vv, wq[d * RANK], aq);
    ak = fmaf(vv, wk[d * RANK], ak);
  }
  q[n * QK + t] = aq;
  k[n * QK + t] = ak;
}

// ---- Kernel C: scores GEMM: S[n-row0][m] = sum_{hr} q[n][hr]*k[m][hr] ----
// 64x64 output tile per block, 256 threads, 4x4 micro-tile (strided by 16).
#define SPAD 132
__global__ void scores_kernel(const float* __restrict__ q,
                              const float* __restrict__ k,
                              float* __restrict__ S, int row0) {
  __shared__ float qs[64][SPAD];
  __shared__ float ks[64][SPAD];
  int tid = threadIdx.x;
  int tx = tid & 15, ty = tid >> 4;
  int brow = row0 + blockIdx.y * 64;
  int bcol = blockIdx.x * 64;
#pragma unroll
  for (int i = 0; i < 8; ++i) {
    int idx = tid + i * 256;  // 0..2047 = 64 rows * 32 float4
    int r = idx >> 5;
    int c = (idx & 31) << 2;
    *(float4*)&qs[r][c] = *(const float4*)&q[(size_t)(brow + r) * QK + c];
    *(float4*)&ks[r][c] = *(const float4*)&k[(size_t)(bcol + r) * QK + c];
  }
  __syncthreads();
  float acc[4][4] = {};
#pragma unroll 8
  for (int d = 0; d < QK; d += 4) {
    float4 a[4], bb[4];
#pragma unroll
    for (int i = 0; i < 4; ++i) a[i] = *(float4*)&qs[ty + 16 * i][d];
#pragma unroll
    for (int j = 0; j < 4; ++j) bb[j] = *(float4*)&ks[tx + 16 * j][d];
#pragma unroll
    for (int i = 0; i < 4; ++i)
#pragma unroll
      for (int j = 0; j < 4; ++j) {
        acc[i][j] = fmaf(a[i].x, bb[j].x, acc[i][j]);
        acc[i][j] = fmaf(a[i].y, bb[j].y, acc[i][j]);
        acc[i][j] = fmaf(a[i].z, bb[j].z, acc[i][j]);
        acc[i][j] = fmaf(a[i].w, bb[j].w, acc[i][j]);
      }
  }
#pragma unroll
  for (int i = 0; i < 4; ++i) {
    size_t rr = (size_t)(brow - row0 + ty + 16 * i) * N_SLOTS;
#pragma unroll
    for (int j = 0; j < 4; ++j) S[rr + bcol + tx + 16 * j] = acc[i][j];
  }
}

// ---- Kernel D: per-row top-32 by |score| via segment-max tournament,
//      then signed softmax + gather-aggregate + unit-normalize. ----
// Segments: 64 segments x 64 elements. Wave 0 keeps segment argmax in
// registers (lane l owns segment l); per selection iteration only the
// dirtied segment is rescanned (64 elems) — no block barriers in the loop.
__global__ void topk_agg_kernel(const float* __restrict__ S,
                                const float* __restrict__ val0,
                                float* __restrict__ out, int row0, int B) {
  __shared__ float s_sc[N_SLOTS];
  __shared__ float s_segv[64];
  __shared__ int s_segi[64];
  __shared__ float s_val[TOPK];
  __shared__ int s_idx[TOPK];
  __shared__ float s_w[TOPK];
  __shared__ float red[4];
  int t = threadIdx.x;
  int lane = t & 63, wid = t >> 6;
  int n = row0 + blockIdx.x;
  const float4* row4 = (const float4*)(S + (size_t)blockIdx.x * N_SLOTS);
#pragma unroll
  for (int j = 0; j < 4; ++j) {
    int i4 = j * 256 + t;
    *(float4*)&s_sc[i4 * 4] = row4[i4];
  }
  __syncthreads();

  // init per-segment argmax: wave `wid` handles segments wid*16..wid*16+15
  for (int s = wid * 16; s < wid * 16 + 16; ++s) {
    int idx = s * 64 + lane;
    float a = fabsf(s_sc[idx]);
#pragma unroll
    for (int o = 32; o > 0; o >>= 1) {
      float oa = __shfl_xor(a, o);
      int oi = __shfl_xor(idx, o);
      if (oa > a || (oa == a && oi < idx)) { a = oa; idx = oi; }
    }
    if (lane == 0) { s_segv[s] = a; s_segi[s] = idx; }
  }
  __syncthreads();

  // wave 0: 32 selection iterations, segment maxima live in registers
  if (wid == 0) {
    float segv = s_segv[lane];
    int segi = s_segi[lane];
    for (int it = 0; it < TOPK; ++it) {
      float a = segv;
      int idx = segi;
#pragma unroll
      for (int o = 32; o > 0; o >>= 1) {
        float oa = __shfl_xor(a, o);
        int oi = __shfl_xor(idx, o);
        if (oa > a || (oa == a && oi < idx)) { a = oa; idx = oi; }
      }
      // all lanes hold the winner (a, idx)
      int seg = idx >> 6;
      if (lane == 0) {
        s_idx[it] = idx;
        s_val[it] = s_sc[idx];
        s_sc[idx] = 0.0f;  // exclude (DS ops are in-order within the wave)
      }
      // rescan dirtied segment
      int ni = seg * 64 + lane;
      float nv = fabsf(s_sc[ni]);
#pragma unroll
      for (int o = 32; o > 0; o >>= 1) {
        float oa = __shfl_xor(nv, o);
        int oi = __shfl_xor(ni, o);
        if (oa > nv || (oa == nv && oi < ni)) { nv = oa; ni = oi; }
      }
      if (lane == seg) { segv = nv; segi = ni; }
    }
    // signed softmax over the 32 selected scores (s_val[0] has max |.|)
    if (lane < TOPK) {
      float sv = s_val[lane];
      float aa = fabsf(sv);
      float mx = fabsf(s_val[0]);
      float e = expf(aa - mx);
      float sum = e;
#pragma unroll
      for (int o = 16; o > 0; o >>= 1) sum += __shfl_xor(sum, o, 32);
      float sgn = (sv > 0.f) ? 1.f : ((sv < 0.f) ? -1.f : 0.f);
      s_w[lane] = sgn * e / sum;
    }
  }
  __syncthreads();

  // aggregate messages + residual + unit-normalize; replicate across batch
  float base = val0[n * DIM + t];
  float msg = 0.f;
#pragma unroll
  for (int kk = 0; kk < TOPK; ++kk)
    msg = fmaf(s_w[kk], val0[(size_t)s_idx[kk] * DIM + t], msg);
  float o = base + msg;
  float ss = block_sum256(o * o, red);
  o *= 1.0f / fmaxf(sqrtf(ss), 1e-6f);
  for (int b = 0; b < B; ++b) out[((size_t)b * N_SLOTS + n) * DIM + t] = o;
}

extern "C" void kernel_launch(void* const* d_in, const int* in_sizes, int n_in,
                              void* d_out, int out_size, void* d_ws, size_t ws_size,
                              hipStream_t stream) {
  // inputs: 0 batch_size, 1 init_state (unused), 2 init_val, 3 ln_gamma,
  //         4 ln_beta, 5 Wq, 6 Wk
  const float* init_val = (const float*)d_in[2];
  const float* g = (const float*)d_in[3];
  const float* b = (const float*)d_in[4];
  const float* Wq = (const float*)d_in[5];
  const float* Wk = (const float*)d_in[6];
  float* out = (float*)d_out;
  int B = out_size / (N_SLOTS * DIM);  // = 4

  // workspace layout: val0 (4MB) | q (2MB) | k (2MB) | S chunk (rest)
  char* ws = (char*)d_ws;
  float* val0 = (float*)ws;
  float* q = (float*)(ws + ((size_t)4 << 20));
  float* k = (float*)(ws + ((size_t)6 << 20));
  float* S = (float*)(ws + ((size_t)8 << 20));
  size_t rem = ws_size > ((size_t)8 << 20) ? ws_size - ((size_t)8 << 20) : 0;
  int rows_chunk = (int)((rem / ((size_t)N_SLOTS * sizeof(float))) / 64) * 64;
  if (rows_chunk > N_SLOTS) rows_chunk = N_SLOTS;
  if (rows_chunk < 64) rows_chunk = 64;  // require ~9MB of ws minimum

  hipLaunchKernelGGL(ln_unit_kernel, dim3(N_SLOTS), dim3(DIM), 0, stream,
                     init_val, g, b, val0);
  hipLaunchKernelGGL(qk_kernel, dim3(N_SLOTS), dim3(QK), 0, stream,
                     val0, Wq, Wk, q, k);
  for (int start = 0; start < N_SLOTS; start += rows_chunk) {
    int rows = N_SLOTS - start;
    if (rows > rows_chunk) rows = rows_chunk;
    hipLaunchKernelGGL(scores_kernel, dim3(N_SLOTS / 64, rows / 64), dim3(256),
                       0, stream, q, k, S, start);
    hipLaunchKernelGGL(topk_agg_kernel, dim3(rows), dim3(256), 0, stream,
                       S, val0, out, start, B);
  }
}

// Round 4
// 229.868 us; speedup vs baseline: 1.3031x; 1.3031x over previous
//
#include <hip/hip_runtime.h>
#include <hip/hip_bf16.h>
#include <math.h>

#define N_SLOTS 4096
#define DIM 256
#define HEADS 4
#define RANK 32
#define TOPK 32
#define QK 128  // HEADS*RANK

typedef __attribute__((ext_vector_type(8))) short short8;   // 8 bf16 = 4 VGPR
typedef __attribute__((ext_vector_type(4))) float f32x4;

// ---- block-wide sum over 256 threads (4 waves) ----
__device__ __forceinline__ float block_sum256(float v, float* red) {
#pragma unroll
  for (int o = 32; o > 0; o >>= 1) v += __shfl_xor(v, o);
  int lane = threadIdx.x & 63, wid = threadIdx.x >> 6;
  if (lane == 0) red[wid] = v;
  __syncthreads();
  v = red[0] + red[1] + red[2] + red[3];
  __syncthreads();
  return v;
}

// ---- Kernel A: LayerNorm + unit-normalize rows of init_val -> val0 [N,D] ----
__global__ void ln_unit_kernel(const float* __restrict__ x,
                               const float* __restrict__ g,
                               const float* __restrict__ b,
                               float* __restrict__ val0) {
  __shared__ float red[4];
  int n = blockIdx.x, t = threadIdx.x;
  float v = x[n * DIM + t];
  float mean = block_sum256(v, red) * (1.0f / DIM);
  float d = v - mean;
  float var = block_sum256(d * d, red) * (1.0f / DIM);
  float y = d * rsqrtf(var + 1e-5f) * g[t] + b[t];
  float ss = block_sum256(y * y, red);
  y = y / fmaxf(sqrtf(ss), 1e-6f);
  val0[n * DIM + t] = y;
}

// ---- Kernel B: q/k projections + bf16 hi/lo split for MFMA operands ----
__global__ void qk2_kernel(const float* __restrict__ val0,
                           const float* __restrict__ Wq,
                           const float* __restrict__ Wk,
                           __hip_bfloat16* __restrict__ qh,
                           __hip_bfloat16* __restrict__ ql,
                           __hip_bfloat16* __restrict__ kh,
                           __hip_bfloat16* __restrict__ kl) {
  __shared__ float v[DIM];
  int n = blockIdx.x, t = threadIdx.x;  // 128 threads
  v[t] = val0[n * DIM + t];
  v[t + 128] = val0[n * DIM + t + 128];
  __syncthreads();
  int h = t >> 5, r = t & 31;
  const float* wq = Wq + (size_t)h * DIM * RANK + r;
  const float* wk = Wk + (size_t)h * DIM * RANK + r;
  float aq = 0.f, ak = 0.f;
#pragma unroll 4
  for (int d = 0; d < DIM; ++d) {
    float vv = v[d];
    aq = fmaf(vv, wq[d * RANK], aq);
    ak = fmaf(vv, wk[d * RANK], ak);
  }
  __hip_bfloat16 h1 = __float2bfloat16(aq);
  qh[n * QK + t] = h1;
  ql[n * QK + t] = __float2bfloat16(aq - __bfloat162float(h1));
  __hip_bfloat16 h2 = __float2bfloat16(ak);
  kh[n * QK + t] = h2;
  kl[n * QK + t] = __float2bfloat16(ak - __bfloat162float(h2));
}

// ---- Kernel C: scores via 16x16x32 bf16 MFMA, 2-way split (hh+hl+lh) ----
// Block: 256 thr = 4 waves; tile 64x64; wave w owns rows [w*16, w*16+16).
// A frag: row=lane&15, k=(lane>>4)*8+j (row-major 16B load). B (=k^T) same.
// C frag: col=lane&15, row=(lane>>4)*4+reg (m89-verified).
__global__ void scores_mfma_kernel(const __hip_bfloat16* __restrict__ qh,
                                   const __hip_bfloat16* __restrict__ ql,
                                   const __hip_bfloat16* __restrict__ kh,
                                   const __hip_bfloat16* __restrict__ kl,
                                   float* __restrict__ S, int row0) {
  int tid = threadIdx.x;
  int w = tid >> 6, l = tid & 63;
  int r = l & 15, g = l >> 4;
  int arow = row0 + blockIdx.y * 64 + w * 16 + r;
  int bcol = blockIdx.x * 64;

  const __hip_bfloat16* qhp = qh + (size_t)arow * QK + g * 8;
  const __hip_bfloat16* qlp = ql + (size_t)arow * QK + g * 8;
  short8 ah[4], al[4];
#pragma unroll
  for (int kc = 0; kc < 4; ++kc) {
    ah[kc] = *(const short8*)(qhp + kc * 32);
    al[kc] = *(const short8*)(qlp + kc * 32);
  }
  f32x4 acc[4];
#pragma unroll
  for (int c = 0; c < 4; ++c) acc[c] = (f32x4){0.f, 0.f, 0.f, 0.f};

#pragma unroll
  for (int c = 0; c < 4; ++c) {
    const __hip_bfloat16* khp = kh + (size_t)(bcol + c * 16 + r) * QK + g * 8;
    const __hip_bfloat16* klp = kl + (size_t)(bcol + c * 16 + r) * QK + g * 8;
#pragma unroll
    for (int kc = 0; kc < 4; ++kc) {
      short8 bh = *(const short8*)(khp + kc * 32);
      short8 bl = *(const short8*)(klp + kc * 32);
      acc[c] = __builtin_amdgcn_mfma_f32_16x16x32_bf16(ah[kc], bh, acc[c], 0, 0, 0);
      acc[c] = __builtin_amdgcn_mfma_f32_16x16x32_bf16(ah[kc], bl, acc[c], 0, 0, 0);
      acc[c] = __builtin_amdgcn_mfma_f32_16x16x32_bf16(al[kc], bh, acc[c], 0, 0, 0);
    }
  }
  int rowl = blockIdx.y * 64 + w * 16 + g * 4;  // chunk-local output row base
#pragma unroll
  for (int c = 0; c < 4; ++c)
#pragma unroll
    for (int reg = 0; reg < 4; ++reg)
      S[(size_t)(rowl + reg) * N_SLOTS + bcol + c * 16 + r] = acc[c][reg];
}

// ---- Kernel D: per-row exact top-32 by |score| via 11/7/7/7-bit radix
//      select (2048-bin LDS histogram round 0 to defeat exponent
//      clustering), then signed softmax + gather-aggregate + normalize. ----
__global__ void topk_agg_kernel(const float* __restrict__ S,
                                const float* __restrict__ val0,
                                float* __restrict__ out, int row0, int B) {
  __shared__ int hist[2048];
  __shared__ int s_wtot[4];
  __shared__ int s_piv[2];
  __shared__ int s_selidx[TOPK];
  __shared__ float s_selval[TOPK];
  __shared__ int s_tiei[64];
  __shared__ float s_tiev[64];
  __shared__ int s_cnt[2];
  __shared__ float s_w[TOPK];
  __shared__ float red[4];

  int t = threadIdx.x, lane = t & 63, wid = t >> 6;
  int n = row0 + blockIdx.x;
  const float4* row4 = (const float4*)(S + (size_t)blockIdx.x * (size_t)N_SLOTS);

  float v[16];
  unsigned key[16];
#pragma unroll
  for (int j = 0; j < 4; ++j) {
    float4 f = row4[j * 256 + t];
    v[4 * j + 0] = f.x; v[4 * j + 1] = f.y;
    v[4 * j + 2] = f.z; v[4 * j + 3] = f.w;
  }
#pragma unroll
  for (int e = 0; e < 16; ++e) key[e] = __float_as_uint(fabsf(v[e]));

  // ---- radix select: exact 32-bit threshold key T of rank TOPK ----
  unsigned prefix = 0u, pmask = 0u;
  int Kr = TOPK;
  const int SH[4] = {21, 14, 7, 0};
  const unsigned BM[4] = {2047u, 127u, 127u, 127u};
#pragma unroll
  for (int rnd = 0; rnd < 4; ++rnd) {
    int shift = SH[rnd];
    unsigned bmask = BM[rnd];
#pragma unroll
    for (int j = 0; j < 8; ++j) hist[t * 8 + j] = 0;
    __syncthreads();
#pragma unroll
    for (int e = 0; e < 16; ++e)
      if ((key[e] & pmask) == prefix)
        atomicAdd(&hist[(key[e] >> shift) & bmask], 1);
    __syncthreads();
    int hl[8], sl[8];
#pragma unroll
    for (int j = 0; j < 8; ++j) hl[j] = hist[t * 8 + j];
    int run = 0;
#pragma unroll
    for (int j = 7; j >= 0; --j) { run += hl[j]; sl[j] = run; }
    // wave-inclusive suffix over per-thread totals
    int ws = run;
#pragma unroll
    for (int o = 1; o < 64; o <<= 1) {
      int tmp = __shfl_down(ws, o);
      if (lane + o < 64) ws += tmp;
    }
    if (lane == 0) s_wtot[wid] = ws;
    __syncthreads();
    int above = ws - run;  // threads above within wave
    for (int ww = wid + 1; ww < 4; ++ww) above += s_wtot[ww];
#pragma unroll
    for (int j = 0; j < 8; ++j) {
      int suf = sl[j] + above;           // count with bin >= (t*8+j)
      if (suf >= Kr && suf - hl[j] < Kr) {
        s_piv[0] = t * 8 + j;
        s_piv[1] = suf - hl[j];          // count strictly greater
      }
    }
    __syncthreads();
    prefix |= ((unsigned)s_piv[0]) << shift;
    pmask |= bmask << shift;
    Kr -= s_piv[1];
    __syncthreads();
  }
  unsigned T = prefix;  // exact rank-TOPK |score| bit pattern

  // ---- compaction: all key>T, plus lowest-index ties at key==T ----
  if (t < 2) s_cnt[t] = 0;
  __syncthreads();
#pragma unroll
  for (int e = 0; e < 16; ++e) {
    int m = (((e >> 2) * 256 + t) << 2) + (e & 3);
    if (key[e] > T) {
      int p = atomicAdd(&s_cnt[0], 1);
      s_selidx[p] = m;
      s_selval[p] = v[e];
    } else if (key[e] == T) {
      int p = atomicAdd(&s_cnt[1], 1);
      if (p < 64) { s_tiei[p] = m; s_tiev[p] = v[e]; }
    }
  }
  __syncthreads();
  int cnt_gt = s_cnt[0];
  int need = TOPK - cnt_gt;  // ties to take, lowest index first
  if (wid == 0) {
    int ce = min(s_cnt[1], 64);
    int cand = (lane < ce) ? s_tiei[lane] : 0x7fffffff;
    float cval = (lane < ce) ? s_tiev[lane] : 0.0f;
    for (int i = 0; i < need; ++i) {
      int mi = cand;
#pragma unroll
      for (int o = 32; o > 0; o >>= 1) mi = min(mi, __shfl_xor(mi, o));
      if (cand == mi) {
        s_selidx[cnt_gt + i] = cand;
        s_selval[cnt_gt + i] = cval;
        cand = 0x7fffffff;
      }
    }
    // ---- signed softmax over the selected 32 (one wave, width-32) ----
    float sv = (lane < TOPK) ? s_selval[lane] : 0.0f;
    float aa = fabsf(sv);
    float mx = aa;
#pragma unroll
    for (int o = 16; o > 0; o >>= 1) mx = fmaxf(mx, __shfl_xor(mx, o, 32));
    float e2 = expf(aa - mx);
    float sum = e2;
#pragma unroll
    for (int o = 16; o > 0; o >>= 1) sum += __shfl_xor(sum, o, 32);
    if (lane < TOPK) {
      float sgn = (sv > 0.f) ? 1.f : ((sv < 0.f) ? -1.f : 0.f);
      s_w[lane] = sgn * e2 / sum;
    }
  }
  __syncthreads();

  // ---- aggregate + residual + unit-normalize; replicate across batch ----
  float base = val0[n * DIM + t];
  float msg = 0.f;
#pragma unroll
  for (int kk = 0; kk < TOPK; ++kk)
    msg = fmaf(s_w[kk], val0[(size_t)s_selidx[kk] * DIM + t], msg);
  float o = base + msg;
  float ss = block_sum256(o * o, red);
  o *= 1.0f / fmaxf(sqrtf(ss), 1e-6f);
  for (int b = 0; b < B; ++b) out[((size_t)b * N_SLOTS + n) * DIM + t] = o;
}

extern "C" void kernel_launch(void* const* d_in, const int* in_sizes, int n_in,
                              void* d_out, int out_size, void* d_ws, size_t ws_size,
                              hipStream_t stream) {
  // inputs: 0 batch_size, 1 init_state (unused), 2 init_val, 3 ln_gamma,
  //         4 ln_beta, 5 Wq, 6 Wk
  const float* init_val = (const float*)d_in[2];
  const float* g = (const float*)d_in[3];
  const float* b = (const float*)d_in[4];
  const float* Wq = (const float*)d_in[5];
  const float* Wk = (const float*)d_in[6];
  float* out = (float*)d_out;
  int B = out_size / (N_SLOTS * DIM);  // = 4

  // workspace: val0 4MB | qh/ql/kh/kl 1MB each | S chunk @8MB
  char* ws = (char*)d_ws;
  float* val0 = (float*)ws;
  __hip_bfloat16* qh = (__hip_bfloat16*)(ws + ((size_t)4 << 20));
  __hip_bfloat16* ql = (__hip_bfloat16*)(ws + ((size_t)5 << 20));
  __hip_bfloat16* kh = (__hip_bfloat16*)(ws + ((size_t)6 << 20));
  __hip_bfloat16* kl = (__hip_bfloat16*)(ws + ((size_t)7 << 20));
  float* S = (float*)(ws + ((size_t)8 << 20));
  size_t rem = ws_size > ((size_t)8 << 20) ? ws_size - ((size_t)8 << 20) : 0;
  int rows_chunk = (int)((rem / ((size_t)N_SLOTS * sizeof(float))) / 64) * 64;
  if (rows_chunk > N_SLOTS) rows_chunk = N_SLOTS;
  if (rows_chunk < 64) rows_chunk = 64;  // require ~9MB of ws minimum

  hipLaunchKernelGGL(ln_unit_kernel, dim3(N_SLOTS), dim3(DIM), 0, stream,
                     init_val, g, b, val0);
  hipLaunchKernelGGL(qk2_kernel, dim3(N_SLOTS), dim3(QK), 0, stream,
                     val0, Wq, Wk, qh, ql, kh, kl);
  for (int start = 0; start < N_SLOTS; start += rows_chunk) {
    int rows = N_SLOTS - start;
    if (rows > rows_chunk) rows = rows_chunk;
    hipLaunchKernelGGL(scores_mfma_kernel, dim3(N_SLOTS / 64, rows / 64),
                       dim3(256), 0, stream, qh, ql, kh, kl, S, start);
    hipLaunchKernelGGL(topk_agg_kernel, dim3(rows), dim3(256), 0, stream,
                       S, val0, out, start, B);
  }
}